// Round 13
// baseline (59.540 us; speedup 1.0000x reference)
//
#include <hip/hip_runtime.h>

// StatefulFormantFilter: B=32, T=48000, F=5
// y[t] = x[t] + 2 r cos(th) y[t-1] - r^2 y[t-2],  r=exp(-pi bw/SR), th=2 pi cf/SR
// x = excitation * (1-r^2) sin(th);  out = sum_f y;  new_states = (y[T-1], y[T-2])
//
// R13: dense-staged L4 rounds (attacks the strided-gather L1 cost with SMALL
// LDS so occupancy survives — the R7 failure mode):
//  - L4=4-step chunks; 64 chunks/round are 1280 CONTIGUOUS floats -> staging
//    is one perfectly-coalesced float4 per thread per array.
//  - K1: 4 rounds {stage, build 4-step maps from LDS, exchange, wave-scan,
//    compose round aggregate into P} -> Gprod only. NO Aws (was 23MB r/t).
//  - K3: prologue Gprod-scan -> S0; 4 rounds {stage, build (coef ONCE,
//    p/q/x kept in regs), scan -> exclusive seeds, replay 4 steps, f-sum,
//    coalesced store}. red unions into bwS, seeds into cfS (dead after use).
// Ledger of closed paths: big-LDS staging (R7), coop grid.sync (R8),
// lookback polls (R10/R11), recompute-vs-cache (R5).

constexpr int B = 32;
constexpr int T = 48000;
constexpr int F = 5;
constexpr int L4 = 4;                     // steps per mini-chunk
constexpr int C4 = T / L4;                // 12000 mini-chunks per chain
constexpr int CPB = 256;                  // mini-chunks per block (1024 steps)
constexpr int NG = (C4 + CPB - 1) / CPB;  // 47 groups
constexpr int NCHAIN = B * F;             // 160
constexpr int THREADS = 320;              // 5 waves
constexpr int NBG = B * NG;               // 1504 blocks
constexpr int NR = 4;                     // rounds of 64 mini-chunks
constexpr int CFS = 28;                   // LDS floats per mini-chunk (20+8 pad)
constexpr int MST = 7;                    // exchange stride
constexpr int XROW = 64 * MST + 1;        // 449

#define CBW2 (-9.4416635e-05f)   // -pi/(48000*ln2)
#define CREV (2.0833333e-05f)    // 1/48000 (revolutions)

__device__ __forceinline__ float fast_exp2(float x) {
#if __has_builtin(__builtin_amdgcn_exp2f)
  return __builtin_amdgcn_exp2f(x);
#else
  return exp2f(x);
#endif
}

__device__ __forceinline__ void coef(float cff, float bwf, float e,
                                     float& p, float& q, float& x) {
  float r = fast_exp2(CBW2 * bwf);
#if __has_builtin(__builtin_amdgcn_sinf) && __has_builtin(__builtin_amdgcn_cosf)
  float rev = CREV * cff;            // v_sin/v_cos take revolutions; rev<0.084
  float sn = __builtin_amdgcn_sinf(rev);
  float cs = __builtin_amdgcn_cosf(rev);
#else
  float th = 6.2831853e+00f * CREV * cff;
  float sn = __sinf(th);
  float cs = __cosf(th);
#endif
  p = 2.f * r * cs;            // -a1
  q = -r * r;                  // -a2
  x = e * fmaf(q, sn, sn);     // e * (1-r^2) sin(th)
}

// Inclusive Hillis-Steele scan of affine maps across a wave (newest-on-left).
__device__ __forceinline__ void wave_scan_maps(int lane, float& u1, float& u2,
                                               float& v1, float& v2,
                                               float& w1, float& w2) {
  #pragma unroll
  for (int d = 1; d < 64; d <<= 1) {
    float pu1 = __shfl_up(u1, d);
    float pv1 = __shfl_up(v1, d);
    float pu2 = __shfl_up(u2, d);
    float pv2 = __shfl_up(v2, d);
    float pw1 = __shfl_up(w1, d);
    float pw2 = __shfl_up(w2, d);
    bool has = (lane >= d);
    pu1 = has ? pu1 : 1.f;  pv1 = has ? pv1 : 0.f;
    pu2 = has ? pu2 : 0.f;  pv2 = has ? pv2 : 1.f;
    pw1 = has ? pw1 : 0.f;  pw2 = has ? pw2 : 0.f;
    float nu1 = fmaf(u1, pu1, v1 * pu2);
    float nv1 = fmaf(u1, pv1, v1 * pv2);
    float nu2 = fmaf(u2, pu1, v2 * pu2);
    float nv2 = fmaf(u2, pv1, v2 * pv2);
    float nw1 = fmaf(u1, pw1, fmaf(v1, pw2, w1));
    float nw2 = fmaf(u2, pw1, fmaf(v2, pw2, w2));
    u1 = nu1; v1 = nv1; u2 = nu2; v2 = nv2; w1 = nw1; w2 = nw2;
  }
}

// Stage one round (64 mini-chunks, contiguous) of cf/bw/ex into LDS.
__device__ __forceinline__ void stage_round(
    float* cfS, float* bwS, float* exS,
    const float* __restrict__ cfrow, const float* __restrict__ bwrow,
    const float* __restrict__ exrow, int g, int r, int tid) {
  int base_e = (g * CPB + r * 64) * L4 * F;   // float index in row
  int e = base_e + 4 * tid;
  if (e > T * F - 4) e = T * F - 4;           // clamp inside row
  float4 vc = *(const float4*)(cfrow + e);
  float4 vb = *(const float4*)(bwrow + e);
  int kc = tid / 5, km = tid % 5;             // 5 float4 per chunk
  *(float4*)&cfS[kc * CFS + 4 * km] = vc;
  *(float4*)&bwS[kc * CFS + 4 * km] = vb;
  if (tid < 64) {
    int e2 = (g * CPB + r * 64) * L4 + 4 * tid;
    if (e2 > T - 4) e2 = T - 4;
    *(float4*)&exS[tid * 4] = *(const float4*)(exrow + e2);
  }
}

__global__ __launch_bounds__(THREADS) void k1_kernel(
    const float* __restrict__ exc, const float* __restrict__ cf,
    const float* __restrict__ bw, float* __restrict__ Gprod) {
  __shared__ float cfS[64 * CFS];
  __shared__ float bwS[64 * CFS];
  __shared__ float exS[64 * 4];
  __shared__ float xch[F][XROW];

  int bg = blockIdx.x;
  int b = bg / NG, g = bg % NG;
  int tid = threadIdx.x;
  int cl = tid / 5, f = tid % 5;
  int w = tid >> 6, lane = tid & 63;

  const float* cfrow = cf + (size_t)b * T * F;
  const float* bwrow = bw + (size_t)b * T * F;
  const float* exrow = exc + (size_t)b * T;

  // running group product (per wave == per formant), identity init
  float P1 = 1.f, P2 = 0.f, P3 = 0.f, P4 = 1.f, P5 = 0.f, P6 = 0.f;

  for (int r = 0; r < NR; ++r) {
    stage_round(cfS, bwS, exS, cfrow, bwrow, exrow, g, r, tid);
    __syncthreads();   // S1: stage ready (also orders prev round's xch reads)

    // build 4-step map from LDS
    {
      float u1 = 1.f, u2 = 0.f, v1 = 0.f, v2 = 1.f, w1 = 0.f, w2 = 0.f;
      int c4g = g * CPB + r * 64 + cl;
      if (c4g < C4) {
        #pragma unroll
        for (int j = 0; j < L4; ++j) {
          float p, q, x;
          coef(cfS[cl * CFS + j * 5 + f], bwS[cl * CFS + j * 5 + f],
               exS[cl * 4 + j], p, q, x);
          float nu = fmaf(p, u1, q * u2);
          float nv = fmaf(p, v1, q * v2);
          float nw = fmaf(p, w1, fmaf(q, w2, x));
          u2 = u1; u1 = nu;
          v2 = v1; v1 = nv;
          w2 = w1; w1 = nw;
        }
      }
      float* m = &xch[f][cl * MST];
      m[0] = u1; m[1] = u2; m[2] = v1; m[3] = v2; m[4] = w1; m[5] = w2;
    }
    __syncthreads();   // S2: exchange ready

    // wave w scans formant w's 64 maps; fold aggregate into P
    {
      const float* s = &xch[w][lane * MST];
      float a1 = s[0], a2 = s[1], a3 = s[2], a4 = s[3], a5 = s[4], a6 = s[5];
      wave_scan_maps(lane, a1, a2, a3, a4, a5, a6);
      float g1 = __shfl(a1, 63), g2 = __shfl(a2, 63), g3 = __shfl(a3, 63);
      float g4 = __shfl(a4, 63), g5 = __shfl(a5, 63), g6 = __shfl(a6, 63);
      // P = A ∘ P
      float n1 = fmaf(g1, P1, g3 * P2);
      float n3 = fmaf(g1, P3, g3 * P4);
      float n2 = fmaf(g2, P1, g4 * P2);
      float n4 = fmaf(g2, P3, g4 * P4);
      float n5 = fmaf(g1, P5, fmaf(g3, P6, g5));
      float n6 = fmaf(g2, P5, fmaf(g4, P6, g6));
      P1 = n1; P2 = n2; P3 = n3; P4 = n4; P5 = n5; P6 = n6;
    }
    // next round's S1 orders these scan-reads vs next xch writes
  }

  if (lane == 0) {
    int chain = b * F + w;
    float4* gp = (float4*)(Gprod + (size_t)(chain * NG + g) * 8);
    gp[0] = make_float4(P1, P2, P3, P4);
    gp[1] = make_float4(P5, P6, 0.f, 0.f);
  }
}

__global__ __launch_bounds__(THREADS) void k3_kernel(
    const float* __restrict__ exc, const float* __restrict__ cf,
    const float* __restrict__ bw, const float* __restrict__ Gprod,
    const float* __restrict__ states0, float* __restrict__ out,
    float* __restrict__ out_states) {
  __shared__ float cfS[64 * CFS];   // seeds union here after build
  __shared__ float bwS[64 * CFS];   // red unions here after build
  __shared__ float exS[64 * 4];
  __shared__ float xch[F][XROW];
  __shared__ float2 sgb[F];

  int bg = blockIdx.x;
  int b = bg / NG, g = bg % NG;
  int tid = threadIdx.x;
  int cl = tid / 5, f = tid % 5;
  int w = tid >> 6, lane = tid & 63;

  const float* cfrow = cf + (size_t)b * T * F;
  const float* bwrow = bw + (size_t)b * T * F;
  const float* exrow = exc + (size_t)b * T;

  // --- prologue: chain prefix over group products (proven R9/R12 pattern) ---
  {
    int chain = b * F + w;
    float u1 = 1.f, u2 = 0.f, v1 = 0.f, v2 = 1.f, w1 = 0.f, w2 = 0.f;
    if (lane < NG) {
      const float4* gp = (const float4*)(Gprod + (size_t)(chain * NG + lane) * 8);
      float4 A0 = gp[0];
      float4 A1 = gp[1];
      u1 = A0.x; u2 = A0.y; v1 = A0.z; v2 = A0.w; w1 = A1.x; w2 = A1.y;
    }
    wave_scan_maps(lane, u1, u2, v1, v2, w1, w2);
    float s01 = states0[chain * 2 + 0];
    float s02 = states0[chain * 2 + 1];
    if (g == 0) {
      if (lane == 0) sgb[w] = make_float2(s01, s02);
      if (lane == NG - 1) {   // full-chain product -> new_states
        out_states[chain * 2 + 0] = fmaf(u1, s01, fmaf(v1, s02, w1));
        out_states[chain * 2 + 1] = fmaf(u2, s01, fmaf(v2, s02, w2));
      }
    } else if (lane == g - 1) {
      sgb[w] = make_float2(fmaf(u1, s01, fmaf(v1, s02, w1)),
                           fmaf(u2, s01, fmaf(v2, s02, w2)));
    }
  }
  __syncthreads();
  float2 S = sgb[w];   // round-entering state, per wave(=formant w), uniform

  for (int r = 0; r < NR; ++r) {
    stage_round(cfS, bwS, exS, cfrow, bwrow, exrow, g, r, tid);
    __syncthreads();   // S1

    // build 4-step map; keep coefs in registers (coef computed ONCE)
    float px[L4], qx[L4], xx[L4];
    int c4g = g * CPB + r * 64 + cl;
    bool val = c4g < C4;
    {
      float u1 = 1.f, u2 = 0.f, v1 = 0.f, v2 = 1.f, w1 = 0.f, w2 = 0.f;
      #pragma unroll
      for (int j = 0; j < L4; ++j) {
        float p, q, x;
        coef(cfS[cl * CFS + j * 5 + f], bwS[cl * CFS + j * 5 + f],
             exS[cl * 4 + j], p, q, x);
        px[j] = p; qx[j] = q; xx[j] = x;
        float nu = fmaf(p, u1, q * u2);
        float nv = fmaf(p, v1, q * v2);
        float nw = fmaf(p, w1, fmaf(q, w2, x));
        u2 = u1; u1 = nu;
        v2 = v1; v1 = nv;
        w2 = w1; w1 = nw;
      }
      if (!val) { u1 = 1.f; u2 = 0.f; v1 = 0.f; v2 = 1.f; w1 = 0.f; w2 = 0.f; }
      float* m = &xch[f][cl * MST];
      m[0] = u1; m[1] = u2; m[2] = v1; m[3] = v2; m[4] = w1; m[5] = w2;
    }
    __syncthreads();   // S2

    // scan + exclusive seeds (w,lane layout); carry update
    {
      const float* s = &xch[w][lane * MST];
      float a1 = s[0], a2 = s[1], a3 = s[2], a4 = s[3], a5 = s[4], a6 = s[5];
      wave_scan_maps(lane, a1, a2, a3, a4, a5, a6);
      float e1 = __shfl_up(a1, 1), e2 = __shfl_up(a2, 1);
      float e3 = __shfl_up(a3, 1), e4 = __shfl_up(a4, 1);
      float e5 = __shfl_up(a5, 1), e6 = __shfl_up(a6, 1);
      if (lane == 0) { e1 = 1.f; e2 = 0.f; e3 = 0.f; e4 = 1.f; e5 = 0.f; e6 = 0.f; }
      float sd1 = fmaf(e1, S.x, fmaf(e3, S.y, e5));
      float sd2 = fmaf(e2, S.x, fmaf(e4, S.y, e6));
      // seed slot for (chunk=lane, formant=w) == linear tid lane*5+w; cfS dead
      ((float2*)cfS)[lane * 5 + w] = make_float2(sd1, sd2);
      // carry across rounds: S = A_round(S)
      float t1 = __shfl(a1, 63), t2 = __shfl(a2, 63), t3 = __shfl(a3, 63);
      float t4 = __shfl(a4, 63), t5 = __shfl(a5, 63), t6 = __shfl(a6, 63);
      float ns1 = fmaf(t1, S.x, fmaf(t3, S.y, t5));
      float ns2 = fmaf(t2, S.x, fmaf(t4, S.y, t6));
      S = make_float2(ns1, ns2);
    }
    __syncthreads();   // S3

    // replay 4 steps from registers (c,f layout); red unions into bwS
    {
      float2 sd = ((float2*)cfS)[tid];
      float y1 = sd.x, y2 = sd.y;
      if (val) {
        #pragma unroll
        for (int j = 0; j < L4; ++j) {
          float y = fmaf(px[j], y1, fmaf(qx[j], y2, xx[j]));
          bwS[f * 321 + cl * 5 + j] = y;   // red[F][321]
          y2 = y1;
          y1 = y;
        }
      }
    }
    __syncthreads();   // S4

    // f-sum + coalesced store (256 steps this round)
    if (tid < 256) {
      int a = (tid >> 2) * 5 + (tid & 3);
      float s = bwS[0 * 321 + a] + bwS[1 * 321 + a] + bwS[2 * 321 + a] +
                bwS[3 * 321 + a] + bwS[4 * 321 + a];
      int step = (g * CPB + r * 64) * L4 + tid;
      if (step < T) out[(size_t)b * T + step] = s;
    }
    __syncthreads();   // S5: reads done before next round overwrites LDS
  }
}

extern "C" void kernel_launch(void* const* d_in, const int* in_sizes, int n_in,
                              void* d_out, int out_size, void* d_ws, size_t ws_size,
                              hipStream_t stream) {
  const float* exc = (const float*)d_in[0];   // (B,T,1)
  const float* cf  = (const float*)d_in[1];   // (B,T,F)
  const float* bw  = (const float*)d_in[2];   // (B,T,F)
  const float* st  = (const float*)d_in[3];   // (B,F,2)
  float* out        = (float*)d_out;          // (B,T,1) then (B,F,2)
  float* out_states = out + (size_t)B * T;

  float* Gprod = (float*)d_ws;                // NCHAIN*NG*8 floats = 240 KB

  k1_kernel<<<NBG, THREADS, 0, stream>>>(exc, cf, bw, Gprod);
  k3_kernel<<<NBG, THREADS, 0, stream>>>(exc, cf, bw, Gprod, st, out,
                                         out_states);
}

// Round 14
// 42.544 us; speedup vs baseline: 1.3995x; 1.3995x over previous
//
#include <hip/hip_runtime.h>

// StatefulFormantFilter: B=32, T=48000, F=5
// y[t] = x[t] + 2 r cos(th) y[t-1] - r^2 y[t-2],  r=exp(-pi bw/SR), th=2 pi cf/SR
// x = excitation * (1-r^2) sin(th);  out = sum_f y;  new_states = (y[T-1], y[T-2])
//
// R14 = R12 verbatim (converged best, 42.5us). Two-sweep chunked affine scan:
// K1: block=(b, 64-chunk group): build 16-step chunk maps (pipelined strided
//     loads), LDS exchange, wave-per-formant inclusive scan -> Aws (6-float
//     maps, cache-resident) + Gprod group products.
// K3: per block: wave-per-formant scan of 47 group products -> chain prefix
//     (g==0 writes new_states); per-(chunk,f) entering state = Aws[c-1](S);
//     replay 16 steps; f-sum via padded LDS; coalesced stores.
// Closed paths (all measured worse): recompute-vs-cache (R5 +12us), big-LDS
// staging (R7 +10.5), coop grid.sync ~75us/sync (R8), lookback acquire-poll
// invalidate-storm (R10) / RMW-poll coherence serialization (R11), small-LDS
// dense staging with L4 rounds (R13 +17). Residual gap vs ~13us/sweep traffic
// floor = L1 line-transaction cost of the (b,t,f)-layout gather (~8us/sweep).

constexpr int B = 32;
constexpr int T = 48000;
constexpr int F = 5;
constexpr int L = 16;          // chunk length
constexpr int C = T / L;       // 3000 chunks per chain
constexpr int GS = 64;         // chunks per group (one wave per formant)
constexpr int NG = (C + GS - 1) / GS;  // 47 groups
constexpr int NCHAIN = B * F;  // 160
constexpr int THREADS = GS * F;        // 320 = 5 waves
constexpr int NBG = B * NG;            // 1504 (b,group) tiles
constexpr int MSTRIDE = 7;             // LDS map stride in floats
constexpr int MROW = GS * MSTRIDE + 1; // 449: row ≡ 1 mod 32 -> bank spread
constexpr int RROW = GS * (L + 1) + 1; // 1089

#define CBW2 (-9.4416635e-05f)   // -pi/(48000*ln2)   (exp2 scale)
#define CREV (2.0833333e-05f)    // 1/48000           (revolutions scale)

__device__ __forceinline__ float fast_exp2(float x) {
#if __has_builtin(__builtin_amdgcn_exp2f)
  return __builtin_amdgcn_exp2f(x);
#else
  return exp2f(x);
#endif
}

__device__ __forceinline__ void coef(float cff, float bwf, float e,
                                     float& p, float& q, float& x) {
  float r = fast_exp2(CBW2 * bwf);
#if __has_builtin(__builtin_amdgcn_sinf) && __has_builtin(__builtin_amdgcn_cosf)
  // v_sin/v_cos take revolutions: sin(2*pi*rev). rev in [0.004,0.084] -> no fract.
  float rev = CREV * cff;
  float sn = __builtin_amdgcn_sinf(rev);
  float cs = __builtin_amdgcn_cosf(rev);
#else
  float th = 6.2831853e+00f * CREV * cff;
  float sn = __sinf(th);
  float cs = __cosf(th);
#endif
  p = 2.f * r * cs;            // -a1
  q = -r * r;                  // -a2
  x = e * fmaf(q, sn, sn);     // e * (1-r^2) sin(th)
}

// Inclusive Hillis-Steele scan of affine maps across a wave (newest-on-left).
__device__ __forceinline__ void wave_scan_maps(int lane, float& u1, float& u2,
                                               float& v1, float& v2,
                                               float& w1, float& w2) {
  #pragma unroll
  for (int d = 1; d < 64; d <<= 1) {
    float pu1 = __shfl_up(u1, d);
    float pv1 = __shfl_up(v1, d);
    float pu2 = __shfl_up(u2, d);
    float pv2 = __shfl_up(v2, d);
    float pw1 = __shfl_up(w1, d);
    float pw2 = __shfl_up(w2, d);
    bool has = (lane >= d);
    pu1 = has ? pu1 : 1.f;  pv1 = has ? pv1 : 0.f;
    pu2 = has ? pu2 : 0.f;  pv2 = has ? pv2 : 1.f;
    pw1 = has ? pw1 : 0.f;  pw2 = has ? pw2 : 0.f;
    float nu1 = fmaf(u1, pu1, v1 * pu2);
    float nv1 = fmaf(u1, pv1, v1 * pv2);
    float nu2 = fmaf(u2, pu1, v2 * pu2);
    float nv2 = fmaf(u2, pv1, v2 * pv2);
    float nw1 = fmaf(u1, pw1, fmaf(v1, pw2, w1));
    float nw2 = fmaf(u2, pw1, fmaf(v2, pw2, w2));
    u1 = nu1; v1 = nv1; u2 = nu2; v2 = nv2; w1 = nw1; w2 = nw2;
  }
}

__global__ __launch_bounds__(THREADS) void k1_kernel(
    const float* __restrict__ exc, const float* __restrict__ cf,
    const float* __restrict__ bw, float* __restrict__ Aws,
    float* __restrict__ Gprod) {
  __shared__ float smaps[F][MROW];

  int bg = blockIdx.x;
  int b = bg / NG, g = bg % NG;
  int tid = threadIdx.x;
  int c_local = tid / F, f = tid % F;
  int c = g * GS + c_local;

  float u1 = 1.f, u2 = 0.f, v1 = 0.f, v2 = 1.f, w1 = 0.f, w2 = 0.f;
  if (c < C) {
    const float* cfp = cf + ((size_t)b * T + c * L) * F + f;
    const float* bwp = bw + ((size_t)b * T + c * L) * F + f;
    const float4* ep4 = (const float4*)(exc + (size_t)b * T + c * L);

    float4 e = ep4[0];
    float cfa[4], bwa[4];
    #pragma unroll
    for (int j = 0; j < 4; ++j) { cfa[j] = cfp[j * F]; bwa[j] = bwp[j * F]; }

    #pragma unroll
    for (int tile = 0; tile < 4; ++tile) {
      float4 en;
      float cfn[4], bwn[4];
      if (tile < 3) {   // issue next tile's loads before computing this one
        en = ep4[tile + 1];
        #pragma unroll
        for (int j = 0; j < 4; ++j) {
          cfn[j] = cfp[(tile * 4 + 4 + j) * F];
          bwn[j] = bwp[(tile * 4 + 4 + j) * F];
        }
      }
      #pragma unroll
      for (int j = 0; j < 4; ++j) {
        float p, q, x;
        coef(cfa[j], bwa[j], (&e.x)[j], p, q, x);
        float nu = fmaf(p, u1, q * u2);
        float nv = fmaf(p, v1, q * v2);
        float nw = fmaf(p, w1, fmaf(q, w2, x));
        u2 = u1; u1 = nu;
        v2 = v1; v1 = nv;
        w2 = w1; w1 = nw;
      }
      if (tile < 3) {
        e = en;
        #pragma unroll
        for (int j = 0; j < 4; ++j) { cfa[j] = cfn[j]; bwa[j] = bwn[j]; }
      }
    }
  }

  {
    float* m = &smaps[f][c_local * MSTRIDE];
    m[0] = u1; m[1] = u2; m[2] = v1; m[3] = v2; m[4] = w1; m[5] = w2;
  }
  __syncthreads();

  int w = tid >> 6, lane = tid & 63;
  const float* s = &smaps[w][lane * MSTRIDE];
  float a1 = s[0], a2 = s[1], a3 = s[2], a4 = s[3], a5 = s[4], a6 = s[5];
  wave_scan_maps(lane, a1, a2, a3, a4, a5, a6);

  int c2 = g * GS + lane;
  int chain = b * F + w;
  if (c2 < C) {
    float2* o = (float2*)(Aws + ((size_t)chain * C + c2) * 6);
    o[0] = make_float2(a1, a2);
    o[1] = make_float2(a3, a4);
    o[2] = make_float2(a5, a6);
  }
  if (lane == 63) {
    float4* gp = (float4*)(Gprod + (size_t)(chain * NG + g) * 8);
    gp[0] = make_float4(a1, a2, a3, a4);
    gp[1] = make_float4(a5, a6, 0.f, 0.f);
  }
}

__global__ __launch_bounds__(THREADS) void k3_kernel(
    const float* __restrict__ exc, const float* __restrict__ cf,
    const float* __restrict__ bw, const float* __restrict__ Aws,
    const float* __restrict__ Gprod, const float* __restrict__ states0,
    float* __restrict__ out, float* __restrict__ out_states) {
  __shared__ float red[F][RROW];
  __shared__ float2 sgb[F];

  int bg = blockIdx.x;
  int b = bg / NG, g = bg % NG;
  int c0 = g * GS;
  int nc = (C - c0 < GS) ? (C - c0) : GS;
  int tid = threadIdx.x;
  int c_local = tid / F, f = tid % F;
  int w = tid >> 6, lane = tid & 63;

  // --- per-block chain prefix: wave w scans formant w's 47 group products ---
  {
    int chain = b * F + w;
    float u1 = 1.f, u2 = 0.f, v1 = 0.f, v2 = 1.f, w1 = 0.f, w2 = 0.f;
    if (lane < NG) {
      const float4* gp = (const float4*)(Gprod + (size_t)(chain * NG + lane) * 8);
      float4 A0 = gp[0];
      float4 A1 = gp[1];
      u1 = A0.x; u2 = A0.y; v1 = A0.z; v2 = A0.w; w1 = A1.x; w2 = A1.y;
    }
    wave_scan_maps(lane, u1, u2, v1, v2, w1, w2);

    float s01 = states0[chain * 2 + 0];
    float s02 = states0[chain * 2 + 1];
    if (g == 0) {
      if (lane == 0) sgb[w] = make_float2(s01, s02);
      if (lane == NG - 1) {   // full-chain product -> new_states (once per chain)
        out_states[chain * 2 + 0] = fmaf(u1, s01, fmaf(v1, s02, w1));
        out_states[chain * 2 + 1] = fmaf(u2, s01, fmaf(v2, s02, w2));
      }
    } else if (lane == g - 1) {  // exclusive prefix before group g
      float sy1 = fmaf(u1, s01, fmaf(v1, s02, w1));
      float sy2 = fmaf(u2, s01, fmaf(v2, s02, w2));
      sgb[w] = make_float2(sy1, sy2);
    }
  }
  __syncthreads();

  // --- replay ---
  if (c_local < nc) {
    int c = c0 + c_local;
    int chain = b * F + f;

    float2 sg = sgb[f];
    float y1, y2;
    if (c_local == 0) {
      y1 = sg.x; y2 = sg.y;
    } else {
      const float2* m = (const float2*)(Aws + ((size_t)chain * C + (c - 1)) * 6);
      float2 M0 = m[0];   // (u1,u2)
      float2 M1 = m[1];   // (v1,v2)
      float2 M2 = m[2];   // (w1,w2)
      y1 = fmaf(M0.x, sg.x, fmaf(M1.x, sg.y, M2.x));
      y2 = fmaf(M0.y, sg.x, fmaf(M1.y, sg.y, M2.y));
    }

    const float* cfp = cf + ((size_t)b * T + c * L) * F + f;
    const float* bwp = bw + ((size_t)b * T + c * L) * F + f;
    const float4* ep4 = (const float4*)(exc + (size_t)b * T + c * L);

    float4 e = ep4[0];
    float cfa[4], bwa[4];
    #pragma unroll
    for (int j = 0; j < 4; ++j) { cfa[j] = cfp[j * F]; bwa[j] = bwp[j * F]; }

    float* rrow = &red[f][c_local * (L + 1)];
    #pragma unroll
    for (int tile = 0; tile < 4; ++tile) {
      float4 en;
      float cfn[4], bwn[4];
      if (tile < 3) {
        en = ep4[tile + 1];
        #pragma unroll
        for (int j = 0; j < 4; ++j) {
          cfn[j] = cfp[(tile * 4 + 4 + j) * F];
          bwn[j] = bwp[(tile * 4 + 4 + j) * F];
        }
      }
      #pragma unroll
      for (int j = 0; j < 4; ++j) {
        float p, q, x;
        coef(cfa[j], bwa[j], (&e.x)[j], p, q, x);
        float y = fmaf(p, y1, fmaf(q, y2, x));
        rrow[tile * 4 + j] = y;
        y2 = y1;
        y1 = y;
      }
      if (tile < 3) {
        e = en;
        #pragma unroll
        for (int j = 0; j < 4; ++j) { cfa[j] = cfn[j]; bwa[j] = bwn[j]; }
      }
    }
  }
  __syncthreads();

  // --- f-sum + coalesced store ---
  int nt = nc * L;
  size_t tbase = (size_t)b * T + (size_t)c0 * L;
  for (int t = tid; t < nt; t += THREADS) {
    int a = (t >> 4) * (L + 1) + (t & (L - 1));
    float s = red[0][a] + red[1][a] + red[2][a] + red[3][a] + red[4][a];
    out[tbase + t] = s;
  }
}

extern "C" void kernel_launch(void* const* d_in, const int* in_sizes, int n_in,
                              void* d_out, int out_size, void* d_ws, size_t ws_size,
                              hipStream_t stream) {
  const float* exc = (const float*)d_in[0];   // (B,T,1)
  const float* cf  = (const float*)d_in[1];   // (B,T,F)
  const float* bw  = (const float*)d_in[2];   // (B,T,F)
  const float* st  = (const float*)d_in[3];   // (B,F,2)
  float* out        = (float*)d_out;          // (B,T,1) then (B,F,2)
  float* out_states = out + (size_t)B * T;

  float* Aws   = (float*)d_ws;                       // NCHAIN*C*6 floats = 11.52 MB
  float* Gprod = Aws + (size_t)NCHAIN * C * 6;       // NCHAIN*NG*8 floats = 240 KB

  k1_kernel<<<NBG, THREADS, 0, stream>>>(exc, cf, bw, Aws, Gprod);
  k3_kernel<<<NBG, THREADS, 0, stream>>>(exc, cf, bw, Aws, Gprod, st, out,
                                         out_states);
}